// Round 3
// baseline (1104.694 us; speedup 1.0000x reference)
//
#include <hip/hip_runtime.h>

#define BB 512
#define TT 2048
#define II 8
#define HH 128
#define OO 96

typedef __attribute__((ext_vector_type(8))) short bf16x8;
typedef __attribute__((ext_vector_type(4))) float f32x4;

#define L2E 1.4426950408889634f

__device__ __forceinline__ float fast_rcp(float x) { return __builtin_amdgcn_rcpf(x); }
__device__ __forceinline__ float exp2_fast(float x) {
#if __has_builtin(__builtin_amdgcn_exp2f)
    return __builtin_amdgcn_exp2f(x);
#else
    return __expf(x * 0.6931471805599453f);   // e^(x ln2) = 2^x
#endif
}
__device__ __forceinline__ unsigned short f2bf(float f) {
    unsigned int u = __builtin_bit_cast(unsigned int, f);
    u += 0x7fffu + ((u >> 16) & 1u);   // RNE
    return (unsigned short)(u >> 16);
}
__device__ __forceinline__ float bf2f(unsigned short h) {
    unsigned int u = ((unsigned int)h) << 16;
    return __builtin_bit_cast(float, u);
}
__device__ __forceinline__ float dot8(const float w[8], float4 a, float4 b, float acc) {
    acc = fmaf(w[0], a.x, acc); acc = fmaf(w[1], a.y, acc);
    acc = fmaf(w[2], a.z, acc); acc = fmaf(w[3], a.w, acc);
    acc = fmaf(w[4], b.x, acc); acc = fmaf(w[5], b.y, acc);
    acc = fmaf(w[6], b.z, acc); acc = fmaf(w[7], b.w, acc);
    return acc;
}

// Block = 4 waves (256 thr), 2 batch rows, full T scan, grid=256 (1 block/CU).
// Wave w owns j in [32w, 32w+32) as TWO MFMA j-blocks (A: 32w+col, B: +16) that
// SHARE the A-fragments (4 ds_read_b128 feed 24 MFMAs). Lane specialization:
// lanes<32 (g4 0,1) finalize j-block A, lanes>=32 (g4 2,3) j-block B -> each lane
// computes exactly ONE gate-set/dot8-set/h: per-SIMD VALU issue per (32j x 2b)
// coverage is HALVED vs the 8-wave layout (which duplicated across g4 pairs).
// MFMA 16x16x32 bf16, K=128 (h only; x-path via fp32 dot8 one step ahead).
//   A-row pattern (m): plane = ((m>>2)&1)*2 + (m&1) over {hi0,lo0,hi1,lo1}
//   gate = C[0] + C[1]  (bf16 hi/lo split compensation); gx+bias folded into C[0] init.
// exp2-folding: r,z weights/biases pre-scaled by -log2(e); n by +2log2(e) -> raw v_exp.
// LDS: 2 bufs x 4 planes x 320B, double-buffered. 1 barrier per step.
__global__ __launch_bounds__(256, 1) void gru_kernel(
    const float* __restrict__ x,     // [B, T, I]
    const float* __restrict__ w_ih,  // [3H, I]
    const float* __restrict__ w_hh,  // [3H, H]
    const float* __restrict__ b_ih,  // [3H]
    const float* __restrict__ b_hh,  // [3H]
    const float* __restrict__ fc_w,  // [O, H]
    const float* __restrict__ fc_b,  // [O]
    float* __restrict__ out)         // [B, O]
{
    __shared__ __align__(16) char hbuf[2 * 1280];
    __shared__ __align__(16) float hfin[2][HH];

    const int tid = threadIdx.x;
    const int wv  = tid >> 6;          // 0..3
    const int ln  = tid & 63;
    const int col = ln & 15;           // C col within tile
    const int g4  = ln >> 4;           // k-subblock of A/B fragment
    const int b   = g4 & 1;            // this lane's batch row
    const int sel = g4 >> 1;           // 0 -> j-block A, 1 -> j-block B
    const int p   = ((ln >> 2) & 1) * 2 + (ln & 1);   // A plane for row=ln&15
    const int jA  = 32 * wv + col;
    const int jB  = jA + 16;
    const int jS  = jA + 16 * sel;     // the j this lane finalizes
    const int b0  = blockIdx.x * 2;

    // ---- B fragments (w_hh -> bf16, weight-stationary, exp2-prescaled) ----
    // B[k=(ln>>4)*8+i][n=ln&15]: lane loads 8 consecutive k from w_hh row (gate,j)
    auto ldfrag_hh = [&](int grow, int ks, float sc) {
        const float* rowp = w_hh + grow * HH + 32 * ks + g4 * 8;
        float4 u = *(const float4*)(rowp);
        float4 v = *(const float4*)(rowp + 4);
        bf16x8 f;
        f[0] = (short)f2bf(sc * u.x); f[1] = (short)f2bf(sc * u.y);
        f[2] = (short)f2bf(sc * u.z); f[3] = (short)f2bf(sc * u.w);
        f[4] = (short)f2bf(sc * v.x); f[5] = (short)f2bf(sc * v.y);
        f[6] = (short)f2bf(sc * v.z); f[7] = (short)f2bf(sc * v.w);
        return f;
    };

    bf16x8 bRA[4], bZA[4], bNA[4], bRB[4], bZB[4], bNB[4];
#pragma unroll
    for (int ks = 0; ks < 4; ++ks) {
        bRA[ks] = ldfrag_hh(jA, ks, -L2E);
        bZA[ks] = ldfrag_hh(HH + jA, ks, -L2E);
        bNA[ks] = ldfrag_hh(2 * HH + jA, ks, 2.0f * L2E);
        bRB[ks] = ldfrag_hh(jB, ks, -L2E);
        bZB[ks] = ldfrag_hh(HH + jB, ks, -L2E);
        bNB[ks] = ldfrag_hh(2 * HH + jB, ks, 2.0f * L2E);
    }

    // ---- w_ih rows for THIS lane's j (fp32, exp2-prescaled) ----
    float wr[8], wz[8], wn[8];
    {
        const float* r0p = w_ih + jS * II;
        const float* r1p = w_ih + (HH + jS) * II;
        const float* r2p = w_ih + (2 * HH + jS) * II;
#pragma unroll
        for (int i = 0; i < 8; ++i) {
            wr[i] = -L2E * r0p[i];
            wz[i] = -L2E * r1p[i];
            wn[i] = (2.0f * L2E) * r2p[i];
        }
    }

    const float bias_r2  = -L2E * (b_ih[jS] + b_hh[jS]);
    const float bias_z2  = -L2E * (b_ih[HH + jS] + b_hh[HH + jS]);
    const float bias_nh2 = (2.0f * L2E) * b_hh[2 * HH + jS];  // inside r*(.), folded into aN init
    const float bias_nx2 = (2.0f * L2E) * b_ih[2 * HH + jS];  // outside, folded into gx dot

    // ---- zero LDS (h=0 both buffers): 2560 B ----
    for (int i = tid; i < 640; i += 256) ((int*)hbuf)[i] = 0;
    __syncthreads();

    const char* abase = hbuf + p * 320 + g4 * 16;
    char* wbase = hbuf + b * 640 + (jS << 1);          // + (1-RBUF)*1280 at use
    const float* xp = x + (size_t)(b0 + b) * TT * II;

    float h0 = 0.f;

    // ---- prologue: gx for t=0,1 (bias folded into dot accumulator) ----
    float gxr0, gxz0, gxn0, gxr1, gxz1, gxn1;
    {
        float4 xa = *(const float4*)(xp);          float4 xb = *(const float4*)(xp + 4);
        float4 xc = *(const float4*)(xp + II);     float4 xd = *(const float4*)(xp + II + 4);
        gxr0 = dot8(wr, xa, xb, bias_r2);  gxz0 = dot8(wz, xa, xb, bias_z2);  gxn0 = dot8(wn, xa, xb, bias_nx2);
        gxr1 = dot8(wr, xc, xd, bias_r2);  gxz1 = dot8(wz, xc, xd, bias_z2);  gxn1 = dot8(wn, xc, xd, bias_nx2);
    }
    float gxr0n, gxz0n, gxn0n, gxr1n, gxz1n, gxn1n;

#define MFMA_BF16 __builtin_amdgcn_mfma_f32_16x16x32_bf16

#define STEP(RBUF, GXR, GXZ, GXN, DOTS)                                         \
    {                                                                           \
        const char* ab = abase + (RBUF) * 1280;                                 \
        bf16x8 a0 = *(const bf16x8*)(ab);                                       \
        bf16x8 a1 = *(const bf16x8*)(ab + 64);                                  \
        bf16x8 a2 = *(const bf16x8*)(ab + 128);                                 \
        bf16x8 a3 = *(const bf16x8*)(ab + 192);                                 \
        f32x4 aRA = {(GXR), 0.f, 0.f, 0.f};                                     \
        f32x4 aZA = {(GXZ), 0.f, 0.f, 0.f};                                     \
        f32x4 aNA = {bias_nh2, 0.f, 0.f, 0.f};                                  \
        f32x4 aRB = {(GXR), 0.f, 0.f, 0.f};                                     \
        f32x4 aZB = {(GXZ), 0.f, 0.f, 0.f};                                     \
        f32x4 aNB = {bias_nh2, 0.f, 0.f, 0.f};                                  \
        float gxn_ = (GXN);                                                     \
        aRA = MFMA_BF16(a0, bRA[0], aRA, 0, 0, 0);                              \
        aZA = MFMA_BF16(a0, bZA[0], aZA, 0, 0, 0);                              \
        aNA = MFMA_BF16(a0, bNA[0], aNA, 0, 0, 0);                              \
        aRB = MFMA_BF16(a0, bRB[0], aRB, 0, 0, 0);                              \
        aZB = MFMA_BF16(a0, bZB[0], aZB, 0, 0, 0);                              \
        aNB = MFMA_BF16(a0, bNB[0], aNB, 0, 0, 0);                              \
        aRA = MFMA_BF16(a1, bRA[1], aRA, 0, 0, 0);                              \
        aZA = MFMA_BF16(a1, bZA[1], aZA, 0, 0, 0);                              \
        aNA = MFMA_BF16(a1, bNA[1], aNA, 0, 0, 0);                              \
        aRB = MFMA_BF16(a1, bRB[1], aRB, 0, 0, 0);                              \
        aZB = MFMA_BF16(a1, bZB[1], aZB, 0, 0, 0);                              \
        aNB = MFMA_BF16(a1, bNB[1], aNB, 0, 0, 0);                              \
        aRA = MFMA_BF16(a2, bRA[2], aRA, 0, 0, 0);                              \
        aZA = MFMA_BF16(a2, bZA[2], aZA, 0, 0, 0);                              \
        aNA = MFMA_BF16(a2, bNA[2], aNA, 0, 0, 0);                              \
        aRB = MFMA_BF16(a2, bRB[2], aRB, 0, 0, 0);                              \
        aZB = MFMA_BF16(a2, bZB[2], aZB, 0, 0, 0);                              \
        aNB = MFMA_BF16(a2, bNB[2], aNB, 0, 0, 0);                              \
        aRA = MFMA_BF16(a3, bRA[3], aRA, 0, 0, 0);                              \
        aZA = MFMA_BF16(a3, bZA[3], aZA, 0, 0, 0);                              \
        aNA = MFMA_BF16(a3, bNA[3], aNA, 0, 0, 0);                              \
        aRB = MFMA_BF16(a3, bRB[3], aRB, 0, 0, 0);                              \
        aZB = MFMA_BF16(a3, bZB[3], aZB, 0, 0, 0);                              \
        aNB = MFMA_BF16(a3, bNB[3], aNB, 0, 0, 0);                              \
        DOTS                                                                    \
        float grA = aRA[0] + aRA[1], grB = aRB[0] + aRB[1];                     \
        float gzA = aZA[0] + aZA[1], gzB = aZB[0] + aZB[1];                     \
        float gnA = aNA[0] + aNA[1], gnB = aNB[0] + aNB[1];                     \
        float gr = sel ? grB : grA;                                             \
        float gz = sel ? gzB : gzA;                                             \
        float gn = sel ? gnB : gnA;                                             \
        float r0 = fast_rcp(1.0f + exp2_fast(gr));                              \
        float z0 = fast_rcp(1.0f + exp2_fast(gz));                              \
        float t0 = fast_rcp(1.0f + exp2_fast(fmaf(r0, gn, gxn_)));              \
        float n0 = fmaf(-2.0f, t0, 1.0f);                                       \
        h0 = fmaf(z0, h0 - n0, n0);                                             \
        {                                                                       \
            char* w_ = wbase + (1 - (RBUF)) * 1280;                             \
            unsigned short s0 = f2bf(h0);                                       \
            *(unsigned short*)(w_)       = s0;                                  \
            *(unsigned short*)(w_ + 320) = f2bf(h0 - bf2f(s0));                 \
        }                                                                       \
        __syncthreads();                                                        \
    }

    for (int it = 0; it < TT / 2; ++it) {
        // prefetch x(t+2), x(t+3) -- consumed by DOTS inside STEP(1)
        int t2 = 2 * it + 2; if (t2 > TT - 1) t2 = TT - 1;
        int t3 = t2 + 1;     if (t3 > TT - 1) t3 = TT - 1;
        float4 pa = *(const float4*)(xp + (size_t)t2 * II);
        float4 pb = *(const float4*)(xp + (size_t)t2 * II + 4);
        float4 pc = *(const float4*)(xp + (size_t)t3 * II);
        float4 pd = *(const float4*)(xp + (size_t)t3 * II + 4);

        STEP(0, gxr0, gxz0, gxn0, {})           // even t: read buf0, write buf1
        STEP(1, gxr1, gxz1, gxn1, {             // odd  t: read buf1, write buf0
            gxr0n = dot8(wr, pa, pb, bias_r2);
            gxz0n = dot8(wz, pa, pb, bias_z2);
            gxn0n = dot8(wn, pa, pb, bias_nx2);
            gxr1n = dot8(wr, pc, pd, bias_r2);
            gxz1n = dot8(wz, pc, pd, bias_z2);
            gxn1n = dot8(wn, pc, pd, bias_nx2);
        })
        gxr0 = gxr0n; gxz0 = gxz0n; gxn0 = gxn0n;
        gxr1 = gxr1n; gxz1 = gxz1n; gxn1 = gxn1n;
    }
#undef STEP
#undef MFMA_BF16

    // ---- epilogue FC on fp32 h: 256 threads = exactly 128j x 2b ----
    hfin[b][jS] = h0;
    __syncthreads();

    if (tid < 2 * OO) {
        const int bb2 = (tid >= OO) ? 1 : 0;
        const int o   = tid - OO * bb2;
        const float4* hf = (const float4*)(&hfin[bb2][0]);
        const float4* wp = (const float4*)(fc_w + o * HH);
        float acc = fc_b[o];
#pragma unroll 8
        for (int v = 0; v < HH / 4; ++v) {
            float4 w4 = wp[v];
            float4 h4 = hf[v];
            acc = fmaf(w4.x, h4.x, acc); acc = fmaf(w4.y, h4.y, acc);
            acc = fmaf(w4.z, h4.z, acc); acc = fmaf(w4.w, h4.w, acc);
        }
        out[(size_t)(b0 + bb2) * OO + o] = acc;
    }
}

extern "C" void kernel_launch(void* const* d_in, const int* in_sizes, int n_in,
                              void* d_out, int out_size, void* d_ws, size_t ws_size,
                              hipStream_t stream) {
    const float* x    = (const float*)d_in[0];
    const float* w_ih = (const float*)d_in[1];
    const float* w_hh = (const float*)d_in[2];
    const float* b_ih = (const float*)d_in[3];
    const float* b_hh = (const float*)d_in[4];
    const float* fc_w = (const float*)d_in[5];
    const float* fc_b = (const float*)d_in[6];
    float* out = (float*)d_out;

    gru_kernel<<<BB / 2, 256, 0, stream>>>(x, w_ih, w_hh, b_ih, b_hh, fc_w, fc_b, out);
}

// Round 4
// 1054.263 us; speedup vs baseline: 1.0478x; 1.0478x over previous
//
#include <hip/hip_runtime.h>

#define BB 512
#define TT 2048
#define II 8
#define HH 128
#define OO 96

typedef __attribute__((ext_vector_type(8))) short bf16x8;
typedef __attribute__((ext_vector_type(4))) float f32x4;

#define L2E 1.4426950408889634f

__device__ __forceinline__ float fast_rcp(float x) { return __builtin_amdgcn_rcpf(x); }
__device__ __forceinline__ float exp2_fast(float x) {
#if __has_builtin(__builtin_amdgcn_exp2f)
    return __builtin_amdgcn_exp2f(x);
#else
    return __expf(x * 0.6931471805599453f);
#endif
}
__device__ __forceinline__ unsigned short f2bf(float f) {
    unsigned int u = __builtin_bit_cast(unsigned int, f);
    u += 0x7fffu + ((u >> 16) & 1u);   // RNE
    return (unsigned short)(u >> 16);
}
__device__ __forceinline__ float bf2f(unsigned short h) {
    unsigned int u = ((unsigned int)h) << 16;
    return __builtin_bit_cast(float, u);
}
__device__ __forceinline__ float dot8(const float w[8], float4 a, float4 b, float acc) {
    acc = fmaf(w[0], a.x, acc); acc = fmaf(w[1], a.y, acc);
    acc = fmaf(w[2], a.z, acc); acc = fmaf(w[3], a.w, acc);
    acc = fmaf(w[4], b.x, acc); acc = fmaf(w[5], b.y, acc);
    acc = fmaf(w[6], b.z, acc); acc = fmaf(w[7], b.w, acc);
    return acc;
}

// Block = 8 waves (512 thr), 2 batch rows, full T scan, grid=256 (1 block/CU).
// Round-2 skeleton (the verified-best schedule: 2 waves/SIMD holds the 96-tile/step
// MFMA floor AND hides the serial chain) with three changes:
//  1. RAW per-step barrier: s_waitcnt lgkmcnt(0) + s_barrier (NOT __syncthreads,
//     which drains vmcnt(0) and serializes the x-prefetch HBM latency into every
//     other step). Only LDS hazards exist at the step barrier; x loads stay in
//     flight and the compiler waits at the dot8 use point.
//  2. exp2-prescaled weights/biases (r,z by -log2e; n by +2log2e) -> raw v_exp2,
//     and gx/bias folded into the MFMA C-init (saves adds + muls per gate).
//  3. No exec-mask guard on the h-write: dup lanes (g4 0/2, 1/3) compute
//     bit-identical h and write identical bytes to identical addresses.
// Wave w owns j-block [16w,16w+16). MFMA 16x16x32 bf16, K=128 (h only; x-path via
// fp32 dot8 one iteration ahead). A-row pattern m: plane=((m>>2)&1)*2+(m&1) over
// {hi0,lo0,hi1,lo1}; lane gate = C[0]+C[1] (bf16 hi/lo split compensation).
// LDS: 2 bufs x 4 planes x 320B, double-buffered, 1 barrier per step.
__global__ __launch_bounds__(512, 2) void gru_kernel(
    const float* __restrict__ x,     // [B, T, I]
    const float* __restrict__ w_ih,  // [3H, I]
    const float* __restrict__ w_hh,  // [3H, H]
    const float* __restrict__ b_ih,  // [3H]
    const float* __restrict__ b_hh,  // [3H]
    const float* __restrict__ fc_w,  // [O, H]
    const float* __restrict__ fc_b,  // [O]
    float* __restrict__ out)         // [B, O]
{
    __shared__ __align__(16) char hbuf[2 * 1280];
    __shared__ __align__(16) float hfin[2][HH];

    const int tid = threadIdx.x;
    const int wv  = tid >> 6;
    const int ln  = tid & 63;
    const int col = ln & 15;       // C col = j within tile
    const int g4  = ln >> 4;       // k-subblock of A/B fragment
    const int b   = g4 & 1;        // this lane's batch row
    const int p   = ((ln >> 2) & 1) * 2 + (ln & 1);   // A plane for row=ln&15
    const int j   = 16 * wv + col;
    const int b0  = blockIdx.x * 2;

    // ---- B fragments (w_hh -> bf16, weight-stationary, exp2-prescaled) ----
    auto ldfrag_hh = [&](int grow, int ks, float sc) {
        const float* rowp = w_hh + grow * HH + 32 * ks + g4 * 8;
        float4 u = *(const float4*)(rowp);
        float4 v = *(const float4*)(rowp + 4);
        bf16x8 f;
        f[0] = (short)f2bf(sc * u.x); f[1] = (short)f2bf(sc * u.y);
        f[2] = (short)f2bf(sc * u.z); f[3] = (short)f2bf(sc * u.w);
        f[4] = (short)f2bf(sc * v.x); f[5] = (short)f2bf(sc * v.y);
        f[6] = (short)f2bf(sc * v.z); f[7] = (short)f2bf(sc * v.w);
        return f;
    };

    bf16x8 bR[4], bZ[4], bN[4];
#pragma unroll
    for (int ks = 0; ks < 4; ++ks) {
        bR[ks] = ldfrag_hh(j, ks, -L2E);
        bZ[ks] = ldfrag_hh(HH + j, ks, -L2E);
        bN[ks] = ldfrag_hh(2 * HH + j, ks, 2.0f * L2E);
    }

    // ---- w_ih rows for this lane's j (fp32, exp2-prescaled) ----
    float wr[8], wz[8], wn[8];
    {
        const float* r0p = w_ih + j * II;
        const float* r1p = w_ih + (HH + j) * II;
        const float* r2p = w_ih + (2 * HH + j) * II;
#pragma unroll
        for (int i = 0; i < 8; ++i) {
            wr[i] = -L2E * r0p[i];
            wz[i] = -L2E * r1p[i];
            wn[i] = (2.0f * L2E) * r2p[i];
        }
    }

    const float bias_r2  = -L2E * (b_ih[j] + b_hh[j]);
    const float bias_z2  = -L2E * (b_ih[HH + j] + b_hh[HH + j]);
    const float bias_nh2 = (2.0f * L2E) * b_hh[2 * HH + j];  // inside r*(.), in aN C-init
    const float bias_nx2 = (2.0f * L2E) * b_ih[2 * HH + j];  // outside, in gx dot

    // ---- zero LDS (h=0 both buffers): 2560 B ----
    for (int i = tid; i < 640; i += 512) ((int*)hbuf)[i] = 0;
    __syncthreads();

    const char* abase = hbuf + p * 320 + g4 * 16;
    char* wbase = hbuf + b * 640 + (j << 1);          // + (1-RBUF)*1280 at use
    const float* xp = x + (size_t)(b0 + b) * TT * II;

    float h0 = 0.f;

    // ---- prologue: gx for t=0,1 (bias folded into dot accumulator) ----
    float gxr0, gxz0, gxn0, gxr1, gxz1, gxn1;
    {
        float4 xa = *(const float4*)(xp);          float4 xb = *(const float4*)(xp + 4);
        float4 xc = *(const float4*)(xp + II);     float4 xd = *(const float4*)(xp + II + 4);
        gxr0 = dot8(wr, xa, xb, bias_r2);  gxz0 = dot8(wz, xa, xb, bias_z2);  gxn0 = dot8(wn, xa, xb, bias_nx2);
        gxr1 = dot8(wr, xc, xd, bias_r2);  gxz1 = dot8(wz, xc, xd, bias_z2);  gxn1 = dot8(wn, xc, xd, bias_nx2);
    }
    float gxr0n, gxz0n, gxn0n, gxr1n, gxz1n, gxn1n;

#define MFMA_BF16 __builtin_amdgcn_mfma_f32_16x16x32_bf16

// Raw step barrier: only LDS hazards cross it. lgkmcnt(0) guarantees this wave's
// ds_writes (and prior ds_reads) are complete; the asm "memory" clobbers fence the
// compiler on both sides so no DS op migrates across.
#define STEP_BARRIER()                                                          \
    asm volatile("s_waitcnt lgkmcnt(0)" ::: "memory");                          \
    __builtin_amdgcn_s_barrier();                                               \
    asm volatile("" ::: "memory");

#define STEP(RBUF, GXR, GXZ, GXN, DOTS)                                         \
    {                                                                           \
        const char* ab = abase + (RBUF) * 1280;                                 \
        bf16x8 a0 = *(const bf16x8*)(ab);                                       \
        bf16x8 a1 = *(const bf16x8*)(ab + 64);                                  \
        bf16x8 a2 = *(const bf16x8*)(ab + 128);                                 \
        bf16x8 a3 = *(const bf16x8*)(ab + 192);                                 \
        f32x4 aR = {(GXR), 0.f, 0.f, 0.f};                                      \
        f32x4 aZ = {(GXZ), 0.f, 0.f, 0.f};                                      \
        f32x4 aN = {bias_nh2, 0.f, 0.f, 0.f};                                   \
        aR = MFMA_BF16(a0, bR[0], aR, 0, 0, 0);                                 \
        aZ = MFMA_BF16(a0, bZ[0], aZ, 0, 0, 0);                                 \
        aN = MFMA_BF16(a0, bN[0], aN, 0, 0, 0);                                 \
        aR = MFMA_BF16(a1, bR[1], aR, 0, 0, 0);                                 \
        aZ = MFMA_BF16(a1, bZ[1], aZ, 0, 0, 0);                                 \
        aN = MFMA_BF16(a1, bN[1], aN, 0, 0, 0);                                 \
        aR = MFMA_BF16(a2, bR[2], aR, 0, 0, 0);                                 \
        aZ = MFMA_BF16(a2, bZ[2], aZ, 0, 0, 0);                                 \
        aN = MFMA_BF16(a2, bN[2], aN, 0, 0, 0);                                 \
        aR = MFMA_BF16(a3, bR[3], aR, 0, 0, 0);                                 \
        aZ = MFMA_BF16(a3, bZ[3], aZ, 0, 0, 0);                                 \
        aN = MFMA_BF16(a3, bN[3], aN, 0, 0, 0);                                 \
        DOTS                                                                    \
        float gr = aR[0] + aR[1];                                               \
        float gz = aZ[0] + aZ[1];                                               \
        float gn = aN[0] + aN[1];                                               \
        float r0 = fast_rcp(1.0f + exp2_fast(gr));                              \
        float z0 = fast_rcp(1.0f + exp2_fast(gz));                              \
        float t0 = fast_rcp(1.0f + exp2_fast(fmaf(r0, gn, (GXN))));             \
        float n0 = fmaf(-2.0f, t0, 1.0f);                                       \
        h0 = fmaf(z0, h0 - n0, n0);                                             \
        {                                                                       \
            char* w_ = wbase + (1 - (RBUF)) * 1280;                             \
            unsigned short s0 = f2bf(h0);                                       \
            *(unsigned short*)(w_)       = s0;                                  \
            *(unsigned short*)(w_ + 320) = f2bf(h0 - bf2f(s0));                 \
        }                                                                       \
        STEP_BARRIER()                                                          \
    }

    for (int it = 0; it < TT / 2; ++it) {
        // prefetch x(t+2), x(t+3) -- consumed by DOTS inside STEP(1).
        // t2/t3 are wave-uniform -> clamp is SALU; loads stay in flight across the
        // raw barriers (no vmcnt drain), compiler waits at the dot8 use.
        int t2 = 2 * it + 2; if (t2 > TT - 1) t2 = TT - 1;
        int t3 = t2 + 1;     if (t3 > TT - 1) t3 = TT - 1;
        float4 pa = *(const float4*)(xp + (size_t)t2 * II);
        float4 pb = *(const float4*)(xp + (size_t)t2 * II + 4);
        float4 pc = *(const float4*)(xp + (size_t)t3 * II);
        float4 pd = *(const float4*)(xp + (size_t)t3 * II + 4);

        STEP(0, gxr0, gxz0, gxn0, {})           // even t: read buf0, write buf1
        STEP(1, gxr1, gxz1, gxn1, {             // odd  t: read buf1, write buf0
            gxr0n = dot8(wr, pa, pb, bias_r2);
            gxz0n = dot8(wz, pa, pb, bias_z2);
            gxn0n = dot8(wn, pa, pb, bias_nx2);
            gxr1n = dot8(wr, pc, pd, bias_r2);
            gxz1n = dot8(wz, pc, pd, bias_z2);
            gxn1n = dot8(wn, pc, pd, bias_nx2);
        })
        gxr0 = gxr0n; gxz0 = gxz0n; gxn0 = gxn0n;
        gxr1 = gxr1n; gxz1 = gxz1n; gxn1 = gxn1n;
    }
#undef STEP
#undef STEP_BARRIER
#undef MFMA_BF16

    // ---- epilogue FC on fp32 h ----
    if (ln < 32) hfin[b][j] = h0;
    __syncthreads();

    if (tid < 2 * OO) {
        const int bb2 = (tid >= OO) ? 1 : 0;
        const int o   = tid - OO * bb2;
        const float4* hf = (const float4*)(&hfin[bb2][0]);
        const float4* wp = (const float4*)(fc_w + o * HH);
        float acc = fc_b[o];
#pragma unroll 8
        for (int v = 0; v < HH / 4; ++v) {
            float4 w4 = wp[v];
            float4 h4 = hf[v];
            acc = fmaf(w4.x, h4.x, acc); acc = fmaf(w4.y, h4.y, acc);
            acc = fmaf(w4.z, h4.z, acc); acc = fmaf(w4.w, h4.w, acc);
        }
        out[(size_t)(b0 + bb2) * OO + o] = acc;
    }
}

extern "C" void kernel_launch(void* const* d_in, const int* in_sizes, int n_in,
                              void* d_out, int out_size, void* d_ws, size_t ws_size,
                              hipStream_t stream) {
    const float* x    = (const float*)d_in[0];
    const float* w_ih = (const float*)d_in[1];
    const float* w_hh = (const float*)d_in[2];
    const float* b_ih = (const float*)d_in[3];
    const float* b_hh = (const float*)d_in[4];
    const float* fc_w = (const float*)d_in[5];
    const float* fc_b = (const float*)d_in[6];
    float* out = (float*)d_out;

    gru_kernel<<<BB / 2, 512, 0, stream>>>(x, w_ih, w_hh, b_ih, b_hh, fc_w, fc_b, out);
}

// Round 5
// 1045.386 us; speedup vs baseline: 1.0567x; 1.0085x over previous
//
#include <hip/hip_runtime.h>

#define BB 512
#define TT 2048
#define II 8
#define HH 128
#define OO 96

typedef __attribute__((ext_vector_type(8))) short bf16x8;
typedef __attribute__((ext_vector_type(4))) float f32x4;

#define L2E 1.4426950408889634f

__device__ __forceinline__ float fast_rcp(float x) { return __builtin_amdgcn_rcpf(x); }
__device__ __forceinline__ float exp2_fast(float x) {
#if __has_builtin(__builtin_amdgcn_exp2f)
    return __builtin_amdgcn_exp2f(x);
#else
    return __expf(x * 0.6931471805599453f);
#endif
}
__device__ __forceinline__ unsigned short f2bf(float f) {
    unsigned int u = __builtin_bit_cast(unsigned int, f);
    u += 0x7fffu + ((u >> 16) & 1u);   // RNE
    return (unsigned short)(u >> 16);
}
__device__ __forceinline__ float bf2f(unsigned short h) {
    unsigned int u = ((unsigned int)h) << 16;
    return __builtin_bit_cast(float, u);
}
__device__ __forceinline__ float dot8(const float w[8], float4 a, float4 b, float acc) {
    acc = fmaf(w[0], a.x, acc); acc = fmaf(w[1], a.y, acc);
    acc = fmaf(w[2], a.z, acc); acc = fmaf(w[3], a.w, acc);
    acc = fmaf(w[4], b.x, acc); acc = fmaf(w[5], b.y, acc);
    acc = fmaf(w[6], b.z, acc); acc = fmaf(w[7], b.w, acc);
    return acc;
}

// Block = 8 waves (512 thr), 2 batch rows, full T scan, grid=256 (1 block/CU).
// EXACT round-2 skeleton (verified best: 2 waves/SIMD holds the 96-tile/step MFMA
// floor and hides the serial chain; __syncthreads barrier — r4 proved the raw
// s_barrier + asm clobbers LOSE scheduling freedom; ln<32 write guard — r4 proved
// unguarded dup-lane LDS writes double bank-conflict cycles) plus the two trims
// r4 proved effective (VALU-only issue dropped ~50 cyc/step):
//  - exp2-prescaled weights/biases (r,z by -log2e; n by +2log2e) -> raw v_exp2
//  - gx/bias folded into the MFMA C-init (kills the post-MFMA adds, shortens tail)
// Wave w owns j-block [16w,16w+16). MFMA 16x16x32 bf16, K=128 (h only; x-path via
// fp32 dot8 one iteration ahead). A-row pattern m: plane=((m>>2)&1)*2+(m&1) over
// {hi0,lo0,hi1,lo1}; lane gate = C[0]+C[1] (bf16 hi/lo split compensation).
// LDS: 2 bufs x 4 planes x 320B, double-buffered, 1 barrier per step.
__global__ __launch_bounds__(512, 2) void gru_kernel(
    const float* __restrict__ x,     // [B, T, I]
    const float* __restrict__ w_ih,  // [3H, I]
    const float* __restrict__ w_hh,  // [3H, H]
    const float* __restrict__ b_ih,  // [3H]
    const float* __restrict__ b_hh,  // [3H]
    const float* __restrict__ fc_w,  // [O, H]
    const float* __restrict__ fc_b,  // [O]
    float* __restrict__ out)         // [B, O]
{
    __shared__ __align__(16) char hbuf[2 * 1280];
    __shared__ __align__(16) float hfin[2][HH];

    const int tid = threadIdx.x;
    const int wv  = tid >> 6;
    const int ln  = tid & 63;
    const int col = ln & 15;       // C col = j within tile
    const int g4  = ln >> 4;       // k-subblock of A/B fragment
    const int b   = g4 & 1;        // this lane's batch row
    const int p   = ((ln >> 2) & 1) * 2 + (ln & 1);   // A plane for row=ln&15
    const int j   = 16 * wv + col;
    const int b0  = blockIdx.x * 2;

    // ---- B fragments (w_hh -> bf16, weight-stationary, exp2-prescaled) ----
    auto ldfrag_hh = [&](int grow, int ks, float sc) {
        const float* rowp = w_hh + grow * HH + 32 * ks + g4 * 8;
        float4 u = *(const float4*)(rowp);
        float4 v = *(const float4*)(rowp + 4);
        bf16x8 f;
        f[0] = (short)f2bf(sc * u.x); f[1] = (short)f2bf(sc * u.y);
        f[2] = (short)f2bf(sc * u.z); f[3] = (short)f2bf(sc * u.w);
        f[4] = (short)f2bf(sc * v.x); f[5] = (short)f2bf(sc * v.y);
        f[6] = (short)f2bf(sc * v.z); f[7] = (short)f2bf(sc * v.w);
        return f;
    };

    bf16x8 bR[4], bZ[4], bN[4];
#pragma unroll
    for (int ks = 0; ks < 4; ++ks) {
        bR[ks] = ldfrag_hh(j, ks, -L2E);
        bZ[ks] = ldfrag_hh(HH + j, ks, -L2E);
        bN[ks] = ldfrag_hh(2 * HH + j, ks, 2.0f * L2E);
    }

    // ---- w_ih rows for this lane's j (fp32, exp2-prescaled) ----
    float wr[8], wz[8], wn[8];
    {
        const float* r0p = w_ih + j * II;
        const float* r1p = w_ih + (HH + j) * II;
        const float* r2p = w_ih + (2 * HH + j) * II;
#pragma unroll
        for (int i = 0; i < 8; ++i) {
            wr[i] = -L2E * r0p[i];
            wz[i] = -L2E * r1p[i];
            wn[i] = (2.0f * L2E) * r2p[i];
        }
    }

    const float bias_r2  = -L2E * (b_ih[j] + b_hh[j]);
    const float bias_z2  = -L2E * (b_ih[HH + j] + b_hh[HH + j]);
    const float bias_nh2 = (2.0f * L2E) * b_hh[2 * HH + j];  // inside r*(.), in aN C-init
    const float bias_nx2 = (2.0f * L2E) * b_ih[2 * HH + j];  // outside, in gx dot

    // ---- zero LDS (h=0 both buffers): 2560 B ----
    for (int i = tid; i < 640; i += 512) ((int*)hbuf)[i] = 0;
    __syncthreads();

    const char* abase = hbuf + p * 320 + g4 * 16;
    char* wbase = hbuf + b * 640 + (j << 1);          // + (1-RBUF)*1280 at use
    const float* xp = x + (size_t)(b0 + b) * TT * II;

    float h0 = 0.f;

    // ---- prologue: gx for t=0,1 (bias folded into dot accumulator) ----
    float gxr0, gxz0, gxn0, gxr1, gxz1, gxn1;
    {
        float4 xa = *(const float4*)(xp);          float4 xb = *(const float4*)(xp + 4);
        float4 xc = *(const float4*)(xp + II);     float4 xd = *(const float4*)(xp + II + 4);
        gxr0 = dot8(wr, xa, xb, bias_r2);  gxz0 = dot8(wz, xa, xb, bias_z2);  gxn0 = dot8(wn, xa, xb, bias_nx2);
        gxr1 = dot8(wr, xc, xd, bias_r2);  gxz1 = dot8(wz, xc, xd, bias_z2);  gxn1 = dot8(wn, xc, xd, bias_nx2);
    }
    float gxr0n, gxz0n, gxn0n, gxr1n, gxz1n, gxn1n;

#define MFMA_BF16 __builtin_amdgcn_mfma_f32_16x16x32_bf16

#define STEP(RBUF, GXR, GXZ, GXN, DOTS)                                         \
    {                                                                           \
        const char* ab = abase + (RBUF) * 1280;                                 \
        bf16x8 a0 = *(const bf16x8*)(ab);                                       \
        bf16x8 a1 = *(const bf16x8*)(ab + 64);                                  \
        bf16x8 a2 = *(const bf16x8*)(ab + 128);                                 \
        bf16x8 a3 = *(const bf16x8*)(ab + 192);                                 \
        f32x4 aR = {(GXR), 0.f, 0.f, 0.f};                                      \
        f32x4 aZ = {(GXZ), 0.f, 0.f, 0.f};                                      \
        f32x4 aN = {bias_nh2, 0.f, 0.f, 0.f};                                   \
        aR = MFMA_BF16(a0, bR[0], aR, 0, 0, 0);                                 \
        aZ = MFMA_BF16(a0, bZ[0], aZ, 0, 0, 0);                                 \
        aN = MFMA_BF16(a0, bN[0], aN, 0, 0, 0);                                 \
        aR = MFMA_BF16(a1, bR[1], aR, 0, 0, 0);                                 \
        aZ = MFMA_BF16(a1, bZ[1], aZ, 0, 0, 0);                                 \
        aN = MFMA_BF16(a1, bN[1], aN, 0, 0, 0);                                 \
        aR = MFMA_BF16(a2, bR[2], aR, 0, 0, 0);                                 \
        aZ = MFMA_BF16(a2, bZ[2], aZ, 0, 0, 0);                                 \
        aN = MFMA_BF16(a2, bN[2], aN, 0, 0, 0);                                 \
        aR = MFMA_BF16(a3, bR[3], aR, 0, 0, 0);                                 \
        aZ = MFMA_BF16(a3, bZ[3], aZ, 0, 0, 0);                                 \
        aN = MFMA_BF16(a3, bN[3], aN, 0, 0, 0);                                 \
        DOTS                                                                    \
        float gr = aR[0] + aR[1];                                               \
        float gz = aZ[0] + aZ[1];                                               \
        float gn = aN[0] + aN[1];                                               \
        float r0 = fast_rcp(1.0f + exp2_fast(gr));                              \
        float z0 = fast_rcp(1.0f + exp2_fast(gz));                              \
        float t0 = fast_rcp(1.0f + exp2_fast(fmaf(r0, gn, (GXN))));             \
        float n0 = fmaf(-2.0f, t0, 1.0f);                                       \
        h0 = fmaf(z0, h0 - n0, n0);                                             \
        if (ln < 32) {                                                          \
            char* w_ = wbase + (1 - (RBUF)) * 1280;                             \
            unsigned short s0 = f2bf(h0);                                       \
            *(unsigned short*)(w_)       = s0;                                  \
            *(unsigned short*)(w_ + 320) = f2bf(h0 - bf2f(s0));                 \
        }                                                                       \
        __syncthreads();                                                        \
    }

    for (int it = 0; it < TT / 2; ++it) {
        // prefetch x(t+2), x(t+3) -- consumed by DOTS inside STEP(1)
        int t2 = 2 * it + 2; if (t2 > TT - 1) t2 = TT - 1;
        int t3 = t2 + 1;     if (t3 > TT - 1) t3 = TT - 1;
        float4 pa = *(const float4*)(xp + (size_t)t2 * II);
        float4 pb = *(const float4*)(xp + (size_t)t2 * II + 4);
        float4 pc = *(const float4*)(xp + (size_t)t3 * II);
        float4 pd = *(const float4*)(xp + (size_t)t3 * II + 4);

        STEP(0, gxr0, gxz0, gxn0, {})           // even t: read buf0, write buf1
        STEP(1, gxr1, gxz1, gxn1, {             // odd  t: read buf1, write buf0
            gxr0n = dot8(wr, pa, pb, bias_r2);
            gxz0n = dot8(wz, pa, pb, bias_z2);
            gxn0n = dot8(wn, pa, pb, bias_nx2);
            gxr1n = dot8(wr, pc, pd, bias_r2);
            gxz1n = dot8(wz, pc, pd, bias_z2);
            gxn1n = dot8(wn, pc, pd, bias_nx2);
        })
        gxr0 = gxr0n; gxz0 = gxz0n; gxn0 = gxn0n;
        gxr1 = gxr1n; gxz1 = gxz1n; gxn1 = gxn1n;
    }
#undef STEP
#undef MFMA_BF16

    // ---- epilogue FC on fp32 h ----
    if (ln < 32) hfin[b][j] = h0;
    __syncthreads();

    if (tid < 2 * OO) {
        const int bb2 = (tid >= OO) ? 1 : 0;
        const int o   = tid - OO * bb2;
        const float4* hf = (const float4*)(&hfin[bb2][0]);
        const float4* wp = (const float4*)(fc_w + o * HH);
        float acc = fc_b[o];
#pragma unroll 8
        for (int v = 0; v < HH / 4; ++v) {
            float4 w4 = wp[v];
            float4 h4 = hf[v];
            acc = fmaf(w4.x, h4.x, acc); acc = fmaf(w4.y, h4.y, acc);
            acc = fmaf(w4.z, h4.z, acc); acc = fmaf(w4.w, h4.w, acc);
        }
        out[(size_t)(b0 + bb2) * OO + o] = acc;
    }
}

extern "C" void kernel_launch(void* const* d_in, const int* in_sizes, int n_in,
                              void* d_out, int out_size, void* d_ws, size_t ws_size,
                              hipStream_t stream) {
    const float* x    = (const float*)d_in[0];
    const float* w_ih = (const float*)d_in[1];
    const float* w_hh = (const float*)d_in[2];
    const float* b_ih = (const float*)d_in[3];
    const float* b_hh = (const float*)d_in[4];
    const float* fc_w = (const float*)d_in[5];
    const float* fc_b = (const float*)d_in[6];
    float* out = (float*)d_out;

    gru_kernel<<<BB / 2, 512, 0, stream>>>(x, w_ih, w_hh, b_ih, b_hh, fc_w, fc_b, out);
}

// Round 6
// 1025.177 us; speedup vs baseline: 1.0776x; 1.0197x over previous
//
#include <hip/hip_runtime.h>

#define BB 512
#define TT 2048
#define II 8
#define HH 128
#define OO 96

typedef __attribute__((ext_vector_type(8))) short bf16x8;
typedef __attribute__((ext_vector_type(4))) float f32x4;

#define L2E 1.4426950408889634f

__device__ __forceinline__ float fast_rcp(float x) { return __builtin_amdgcn_rcpf(x); }
__device__ __forceinline__ float exp2_fast(float x) {
#if __has_builtin(__builtin_amdgcn_exp2f)
    return __builtin_amdgcn_exp2f(x);
#else
    return __expf(x * 0.6931471805599453f);
#endif
}
__device__ __forceinline__ unsigned short f2bf(float f) {
    unsigned int u = __builtin_bit_cast(unsigned int, f);
    u += 0x7fffu + ((u >> 16) & 1u);   // RNE
    return (unsigned short)(u >> 16);
}
__device__ __forceinline__ float bf2f(unsigned short h) {
    unsigned int u = ((unsigned int)h) << 16;
    return __builtin_bit_cast(float, u);
}
__device__ __forceinline__ float dot8(const float w[8], float4 a, float4 b, float acc) {
    acc = fmaf(w[0], a.x, acc); acc = fmaf(w[1], a.y, acc);
    acc = fmaf(w[2], a.z, acc); acc = fmaf(w[3], a.w, acc);
    acc = fmaf(w[4], b.x, acc); acc = fmaf(w[5], b.y, acc);
    acc = fmaf(w[6], b.z, acc); acc = fmaf(w[7], b.w, acc);
    return acc;
}

// Block = 8 waves (512 thr), 2 batch rows, full T scan, grid=256 (1 block/CU).
// EXACT round-2 skeleton — verified best across r0..r5: 2 waves/SIMD, __syncthreads
// step barrier (r4: raw s_barrier +60cyc/step), ln<32 write guard (r4: unguarded
// doubles LDS write bank-conflicts), ZERO-init MFMA accumulators (r5: folding gx
// into C-init delays MFMA-phase start behind 12 dependent v_movs -> +60cyc/step).
// Latency-surgery on the tail (the step is schedule/latency-bound, NOT issue-bound;
// r4/r5 proved instruction-count cuts don't move it):
//  - exp2-prescaled weights/biases (r,z by -log2e; n by +2log2e) -> raw v_exp2.
//  - each gate's 4-deep MFMA accumulate chain split into 2x2-deep (aX0/aX1):
//    gate result ready ~2 MFMA latencies earlier.
//  - MFMA program order: R,N chains first, Z last — the serial tail consumes
//    r first (exp->rcp), then gn, z only at the final fma; tail starts ~4 issue
//    slots earlier and overlaps the Z MFMAs.
// Wave w owns j-block [16w,16w+16). MFMA 16x16x32 bf16, K=128 (h only; x-path via
// fp32 dot8 one iteration ahead). A-row pattern m: plane=((m>>2)&1)*2+(m&1) over
// {hi0,lo0,hi1,lo1}; lane gate = C[0]+C[1] (bf16 hi/lo split compensation).
// LDS: 2 bufs x 4 planes x 320B, double-buffered, 1 barrier per step.
__global__ __launch_bounds__(512, 2) void gru_kernel(
    const float* __restrict__ x,     // [B, T, I]
    const float* __restrict__ w_ih,  // [3H, I]
    const float* __restrict__ w_hh,  // [3H, H]
    const float* __restrict__ b_ih,  // [3H]
    const float* __restrict__ b_hh,  // [3H]
    const float* __restrict__ fc_w,  // [O, H]
    const float* __restrict__ fc_b,  // [O]
    float* __restrict__ out)         // [B, O]
{
    __shared__ __align__(16) char hbuf[2 * 1280];
    __shared__ __align__(16) float hfin[2][HH];

    const int tid = threadIdx.x;
    const int wv  = tid >> 6;
    const int ln  = tid & 63;
    const int col = ln & 15;       // C col = j within tile
    const int g4  = ln >> 4;       // k-subblock of A/B fragment
    const int b   = g4 & 1;        // this lane's batch row
    const int p   = ((ln >> 2) & 1) * 2 + (ln & 1);   // A plane for row=ln&15
    const int j   = 16 * wv + col;
    const int b0  = blockIdx.x * 2;

    // ---- B fragments (w_hh -> bf16, weight-stationary, exp2-prescaled) ----
    auto ldfrag_hh = [&](int grow, int ks, float sc) {
        const float* rowp = w_hh + grow * HH + 32 * ks + g4 * 8;
        float4 u = *(const float4*)(rowp);
        float4 v = *(const float4*)(rowp + 4);
        bf16x8 f;
        f[0] = (short)f2bf(sc * u.x); f[1] = (short)f2bf(sc * u.y);
        f[2] = (short)f2bf(sc * u.z); f[3] = (short)f2bf(sc * u.w);
        f[4] = (short)f2bf(sc * v.x); f[5] = (short)f2bf(sc * v.y);
        f[6] = (short)f2bf(sc * v.z); f[7] = (short)f2bf(sc * v.w);
        return f;
    };

    bf16x8 bR[4], bZ[4], bN[4];
#pragma unroll
    for (int ks = 0; ks < 4; ++ks) {
        bR[ks] = ldfrag_hh(j, ks, -L2E);
        bZ[ks] = ldfrag_hh(HH + j, ks, -L2E);
        bN[ks] = ldfrag_hh(2 * HH + j, ks, 2.0f * L2E);
    }

    // ---- w_ih rows for this lane's j (fp32, exp2-prescaled) ----
    float wr[8], wz[8], wn[8];
    {
        const float* r0p = w_ih + j * II;
        const float* r1p = w_ih + (HH + j) * II;
        const float* r2p = w_ih + (2 * HH + j) * II;
#pragma unroll
        for (int i = 0; i < 8; ++i) {
            wr[i] = -L2E * r0p[i];
            wz[i] = -L2E * r1p[i];
            wn[i] = (2.0f * L2E) * r2p[i];
        }
    }

    const float bias_r2  = -L2E * (b_ih[j] + b_hh[j]);
    const float bias_z2  = -L2E * (b_ih[HH + j] + b_hh[HH + j]);
    const float bias_nh2 = (2.0f * L2E) * b_hh[2 * HH + j];  // inside r*(.), added in tail
    const float bias_nx2 = (2.0f * L2E) * b_ih[2 * HH + j];  // outside, in gx dot

    // ---- zero LDS (h=0 both buffers): 2560 B ----
    for (int i = tid; i < 640; i += 512) ((int*)hbuf)[i] = 0;
    __syncthreads();

    const char* abase = hbuf + p * 320 + g4 * 16;
    char* wbase = hbuf + b * 640 + (j << 1);          // + (1-RBUF)*1280 at use
    const float* xp = x + (size_t)(b0 + b) * TT * II;

    float h0 = 0.f;
    const f32x4 zf = {0.f, 0.f, 0.f, 0.f};

    // ---- prologue: gx for t=0,1 (bias folded into dot accumulator) ----
    float gxr0, gxz0, gxn0, gxr1, gxz1, gxn1;
    {
        float4 xa = *(const float4*)(xp);          float4 xb = *(const float4*)(xp + 4);
        float4 xc = *(const float4*)(xp + II);     float4 xd = *(const float4*)(xp + II + 4);
        gxr0 = dot8(wr, xa, xb, bias_r2);  gxz0 = dot8(wz, xa, xb, bias_z2);  gxn0 = dot8(wn, xa, xb, bias_nx2);
        gxr1 = dot8(wr, xc, xd, bias_r2);  gxz1 = dot8(wz, xc, xd, bias_z2);  gxn1 = dot8(wn, xc, xd, bias_nx2);
    }
    float gxr0n, gxz0n, gxn0n, gxr1n, gxz1n, gxn1n;

#define MFMA_BF16 __builtin_amdgcn_mfma_f32_16x16x32_bf16

#define STEP(RBUF, GXR, GXZ, GXN, DOTS)                                         \
    {                                                                           \
        const char* ab = abase + (RBUF) * 1280;                                 \
        bf16x8 a0 = *(const bf16x8*)(ab);                                       \
        bf16x8 a1 = *(const bf16x8*)(ab + 64);                                  \
        bf16x8 a2 = *(const bf16x8*)(ab + 128);                                 \
        bf16x8 a3 = *(const bf16x8*)(ab + 192);                                 \
        f32x4 aR0 = zf, aR1 = zf, aN0 = zf, aN1 = zf, aZ0 = zf, aZ1 = zf;       \
        /* R and N chains first (tail consumes r, then gn) */                   \
        aR0 = MFMA_BF16(a0, bR[0], aR0, 0, 0, 0);                               \
        aN0 = MFMA_BF16(a0, bN[0], aN0, 0, 0, 0);                               \
        aR0 = MFMA_BF16(a1, bR[1], aR0, 0, 0, 0);                               \
        aN0 = MFMA_BF16(a1, bN[1], aN0, 0, 0, 0);                               \
        aR1 = MFMA_BF16(a2, bR[2], aR1, 0, 0, 0);                               \
        aN1 = MFMA_BF16(a2, bN[2], aN1, 0, 0, 0);                               \
        aR1 = MFMA_BF16(a3, bR[3], aR1, 0, 0, 0);                               \
        aN1 = MFMA_BF16(a3, bN[3], aN1, 0, 0, 0);                               \
        /* Z last (consumed only by the final h-update fma) */                  \
        aZ0 = MFMA_BF16(a0, bZ[0], aZ0, 0, 0, 0);                               \
        aZ1 = MFMA_BF16(a2, bZ[2], aZ1, 0, 0, 0);                               \
        aZ0 = MFMA_BF16(a1, bZ[1], aZ0, 0, 0, 0);                               \
        aZ1 = MFMA_BF16(a3, bZ[3], aZ1, 0, 0, 0);                               \
        DOTS                                                                    \
        float gr = (aR0[0] + aR0[1]) + (aR1[0] + aR1[1] + (GXR));               \
        float r0 = fast_rcp(1.0f + exp2_fast(gr));                              \
        float gn = (aN0[0] + aN0[1]) + (aN1[0] + aN1[1] + bias_nh2);            \
        float t0 = fast_rcp(1.0f + exp2_fast(fmaf(r0, gn, (GXN))));             \
        float n0 = fmaf(-2.0f, t0, 1.0f);                                       \
        float gz = (aZ0[0] + aZ0[1]) + (aZ1[0] + aZ1[1] + (GXZ));               \
        float z0 = fast_rcp(1.0f + exp2_fast(gz));                              \
        h0 = fmaf(z0, h0 - n0, n0);                                             \
        if (ln < 32) {                                                          \
            char* w_ = wbase + (1 - (RBUF)) * 1280;                             \
            unsigned short s0 = f2bf(h0);                                       \
            *(unsigned short*)(w_)       = s0;                                  \
            *(unsigned short*)(w_ + 320) = f2bf(h0 - bf2f(s0));                 \
        }                                                                       \
        __syncthreads();                                                        \
    }

    for (int it = 0; it < TT / 2; ++it) {
        // prefetch x(t+2), x(t+3) -- consumed by DOTS inside STEP(1)
        int t2 = 2 * it + 2; if (t2 > TT - 1) t2 = TT - 1;
        int t3 = t2 + 1;     if (t3 > TT - 1) t3 = TT - 1;
        float4 pa = *(const float4*)(xp + (size_t)t2 * II);
        float4 pb = *(const float4*)(xp + (size_t)t2 * II + 4);
        float4 pc = *(const float4*)(xp + (size_t)t3 * II);
        float4 pd = *(const float4*)(xp + (size_t)t3 * II + 4);

        STEP(0, gxr0, gxz0, gxn0, {})           // even t: read buf0, write buf1
        STEP(1, gxr1, gxz1, gxn1, {             // odd  t: read buf1, write buf0
            gxr0n = dot8(wr, pa, pb, bias_r2);
            gxz0n = dot8(wz, pa, pb, bias_z2);
            gxn0n = dot8(wn, pa, pb, bias_nx2);
            gxr1n = dot8(wr, pc, pd, bias_r2);
            gxz1n = dot8(wz, pc, pd, bias_z2);
            gxn1n = dot8(wn, pc, pd, bias_nx2);
        })
        gxr0 = gxr0n; gxz0 = gxz0n; gxn0 = gxn0n;
        gxr1 = gxr1n; gxz1 = gxz1n; gxn1 = gxn1n;
    }
#undef STEP
#undef MFMA_BF16

    // ---- epilogue FC on fp32 h ----
    if (ln < 32) hfin[b][j] = h0;
    __syncthreads();

    if (tid < 2 * OO) {
        const int bb2 = (tid >= OO) ? 1 : 0;
        const int o   = tid - OO * bb2;
        const float4* hf = (const float4*)(&hfin[bb2][0]);
        const float4* wp = (const float4*)(fc_w + o * HH);
        float acc = fc_b[o];
#pragma unroll 8
        for (int v = 0; v < HH / 4; ++v) {
            float4 w4 = wp[v];
            float4 h4 = hf[v];
            acc = fmaf(w4.x, h4.x, acc); acc = fmaf(w4.y, h4.y, acc);
            acc = fmaf(w4.z, h4.z, acc); acc = fmaf(w4.w, h4.w, acc);
        }
        out[(size_t)(b0 + bb2) * OO + o] = acc;
    }
}

extern "C" void kernel_launch(void* const* d_in, const int* in_sizes, int n_in,
                              void* d_out, int out_size, void* d_ws, size_t ws_size,
                              hipStream_t stream) {
    const float* x    = (const float*)d_in[0];
    const float* w_ih = (const float*)d_in[1];
    const float* w_hh = (const float*)d_in[2];
    const float* b_ih = (const float*)d_in[3];
    const float* b_hh = (const float*)d_in[4];
    const float* fc_w = (const float*)d_in[5];
    const float* fc_b = (const float*)d_in[6];
    float* out = (float*)d_out;

    gru_kernel<<<BB / 2, 512, 0, stream>>>(x, w_ih, w_hh, b_ih, b_hh, fc_w, fc_b, out);
}

// Round 7
// 914.569 us; speedup vs baseline: 1.2079x; 1.1209x over previous
//
#include <hip/hip_runtime.h>

#define BB 512
#define TT 2048
#define II 8
#define HH 128
#define OO 96

typedef __attribute__((ext_vector_type(8))) short bf16x8;
typedef __attribute__((ext_vector_type(4))) float f32x4;

#define L2E 1.4426950408889634f

__device__ __forceinline__ float fast_rcp(float x) { return __builtin_amdgcn_rcpf(x); }
__device__ __forceinline__ float exp2_fast(float x) {
#if __has_builtin(__builtin_amdgcn_exp2f)
    return __builtin_amdgcn_exp2f(x);
#else
    return __expf(x * 0.6931471805599453f);
#endif
}
__device__ __forceinline__ unsigned short f2bf(float f) {
    unsigned int u = __builtin_bit_cast(unsigned int, f);
    u += 0x7fffu + ((u >> 16) & 1u);   // RNE
    return (unsigned short)(u >> 16);
}
__device__ __forceinline__ float bf2f(unsigned short h) {
    unsigned int u = ((unsigned int)h) << 16;
    return __builtin_bit_cast(float, u);
}
__device__ __forceinline__ float dot8(const float w[8], float4 a, float4 b, float acc) {
    acc = fmaf(w[0], a.x, acc); acc = fmaf(w[1], a.y, acc);
    acc = fmaf(w[2], a.z, acc); acc = fmaf(w[3], a.w, acc);
    acc = fmaf(w[4], b.x, acc); acc = fmaf(w[5], b.y, acc);
    acc = fmaf(w[6], b.z, acc); acc = fmaf(w[7], b.w, acc);
    return acc;
}

// Block = 8 waves (512 thr), 2 batch rows, full T scan, grid=256 (1 block/CU).
// EXACT round-2 skeleton (best across r0..r6: 2 waves/SIMD, __syncthreads step
// barrier, ln<32 write guard, zero-init accumulators, 4-deep R/Z/N chains in
// ks-major order) + the last untried issue-lever:
//  ROLE-SPLIT r/z SIGMOID SHARING. Lanes (col,g4) and (col,g4+2) compute
//  identical (j,b) gates; instead of duplicating, lo-lanes (ln<32) evaluate the
//  r-sigmoid and hi-lanes the z-sigmoid through the SAME instruction stream
//  (cndmask accumulator select + role-split dot weights); one __shfl_xor(.,32)
//  delivers z to the lo-lanes (off critical path — ready ~100cyc before use).
//  Removes per wave-step: 1 dot8 (8 fma) + 1 exp2 + 1 rcp + 1 add.
//  Also: x-dots rebalanced 2/2 across STEP(0)/STEP(1) (was 0/6 -> STEP(1) skew).
// exp2-prescale kept: weights/biases r,z by -log2e; n by +2log2e -> raw v_exp2.
// Wave w owns j-block [16w,16w+16). MFMA 16x16x32 bf16, K=128 (h only; x-path via
// fp32 dot8 one iteration ahead). A-row pattern m: plane=((m>>2)&1)*2+(m&1) over
// {hi0,lo0,hi1,lo1}; lane gate = C[0]+C[1] (bf16 hi/lo split compensation).
// LDS: 2 bufs x 4 planes x 320B, double-buffered, 1 barrier per step.
__global__ __launch_bounds__(512, 2) void gru_kernel(
    const float* __restrict__ x,     // [B, T, I]
    const float* __restrict__ w_ih,  // [3H, I]
    const float* __restrict__ w_hh,  // [3H, H]
    const float* __restrict__ b_ih,  // [3H]
    const float* __restrict__ b_hh,  // [3H]
    const float* __restrict__ fc_w,  // [O, H]
    const float* __restrict__ fc_b,  // [O]
    float* __restrict__ out)         // [B, O]
{
    __shared__ __align__(16) char hbuf[2 * 1280];
    __shared__ __align__(16) float hfin[2][HH];

    const int tid = threadIdx.x;
    const int wv  = tid >> 6;
    const int ln  = tid & 63;
    const int col = ln & 15;       // C col = j within tile
    const int g4  = ln >> 4;       // k-subblock of A/B fragment
    const int b   = g4 & 1;        // this lane's batch row
    const int sel = (ln >= 32);    // 0: finalize r-chain; 1: finalize z-chain
    const int p   = ((ln >> 2) & 1) * 2 + (ln & 1);   // A plane for row=ln&15
    const int j   = 16 * wv + col;
    const int b0  = blockIdx.x * 2;

    // ---- B fragments (w_hh -> bf16, weight-stationary, exp2-prescaled) ----
    auto ldfrag_hh = [&](int grow, int ks, float sc) {
        const float* rowp = w_hh + grow * HH + 32 * ks + g4 * 8;
        float4 u = *(const float4*)(rowp);
        float4 v = *(const float4*)(rowp + 4);
        bf16x8 f;
        f[0] = (short)f2bf(sc * u.x); f[1] = (short)f2bf(sc * u.y);
        f[2] = (short)f2bf(sc * u.z); f[3] = (short)f2bf(sc * u.w);
        f[4] = (short)f2bf(sc * v.x); f[5] = (short)f2bf(sc * v.y);
        f[6] = (short)f2bf(sc * v.z); f[7] = (short)f2bf(sc * v.w);
        return f;
    };

    bf16x8 bR[4], bZ[4], bN[4];
#pragma unroll
    for (int ks = 0; ks < 4; ++ks) {
        bR[ks] = ldfrag_hh(j, ks, -L2E);
        bZ[ks] = ldfrag_hh(HH + j, ks, -L2E);
        bN[ks] = ldfrag_hh(2 * HH + j, ks, 2.0f * L2E);
    }

    // ---- w_ih rows for this lane's role (fp32, exp2-prescaled) ----
    // lo-lanes: r-row; hi-lanes: z-row. n-row on all lanes.
    const int rz_row = sel ? (HH + j) : j;
    float wrz[8], wn[8];
    {
        const float* rzp = w_ih + rz_row * II;
        const float* r2p = w_ih + (2 * HH + j) * II;
#pragma unroll
        for (int i = 0; i < 8; ++i) {
            wrz[i] = -L2E * rzp[i];
            wn[i]  = (2.0f * L2E) * r2p[i];
        }
    }

    const float bias_rz2 = -L2E * (b_ih[rz_row] + b_hh[rz_row]);
    const float bias_nh2 = (2.0f * L2E) * b_hh[2 * HH + j];  // inside r*(.), added in tail
    const float bias_nx2 = (2.0f * L2E) * b_ih[2 * HH + j];  // outside, in gx dot

    // ---- zero LDS (h=0 both buffers): 2560 B ----
    for (int i = tid; i < 640; i += 512) ((int*)hbuf)[i] = 0;
    __syncthreads();

    const char* abase = hbuf + p * 320 + g4 * 16;
    char* wbase = hbuf + b * 640 + (j << 1);          // + (1-RBUF)*1280 at use
    const float* xp = x + (size_t)(b0 + b) * TT * II;

    float h0 = 0.f;
    const f32x4 zf = {0.f, 0.f, 0.f, 0.f};

    // ---- prologue: gx for t=0,1 (bias folded into dot accumulator) ----
    float grz0, gn0, grz1, gn1;
    {
        float4 xa = *(const float4*)(xp);          float4 xb = *(const float4*)(xp + 4);
        float4 xc = *(const float4*)(xp + II);     float4 xd = *(const float4*)(xp + II + 4);
        grz0 = dot8(wrz, xa, xb, bias_rz2);  gn0 = dot8(wn, xa, xb, bias_nx2);
        grz1 = dot8(wrz, xc, xd, bias_rz2);  gn1 = dot8(wn, xc, xd, bias_nx2);
    }
    float grz0n, gn0n, grz1n, gn1n;

#define MFMA_BF16 __builtin_amdgcn_mfma_f32_16x16x32_bf16

#define STEP(RBUF, GRZ, GXN, DOTS)                                              \
    {                                                                           \
        const char* ab = abase + (RBUF) * 1280;                                 \
        bf16x8 a0 = *(const bf16x8*)(ab);                                       \
        bf16x8 a1 = *(const bf16x8*)(ab + 64);                                  \
        bf16x8 a2 = *(const bf16x8*)(ab + 128);                                 \
        bf16x8 a3 = *(const bf16x8*)(ab + 192);                                 \
        f32x4 aR = zf, aZ = zf, aN = zf;                                        \
        aR = MFMA_BF16(a0, bR[0], aR, 0, 0, 0);                                 \
        aZ = MFMA_BF16(a0, bZ[0], aZ, 0, 0, 0);                                 \
        aN = MFMA_BF16(a0, bN[0], aN, 0, 0, 0);                                 \
        aR = MFMA_BF16(a1, bR[1], aR, 0, 0, 0);                                 \
        aZ = MFMA_BF16(a1, bZ[1], aZ, 0, 0, 0);                                 \
        aN = MFMA_BF16(a1, bN[1], aN, 0, 0, 0);                                 \
        aR = MFMA_BF16(a2, bR[2], aR, 0, 0, 0);                                 \
        aZ = MFMA_BF16(a2, bZ[2], aZ, 0, 0, 0);                                 \
        aN = MFMA_BF16(a2, bN[2], aN, 0, 0, 0);                                 \
        aR = MFMA_BF16(a3, bR[3], aR, 0, 0, 0);                                 \
        aZ = MFMA_BF16(a3, bZ[3], aZ, 0, 0, 0);                                 \
        aN = MFMA_BF16(a3, bN[3], aN, 0, 0, 0);                                 \
        DOTS                                                                    \
        float c0 = sel ? aZ[0] : aR[0];                                         \
        float c1 = sel ? aZ[1] : aR[1];                                         \
        float grz = c0 + c1 + (GRZ);                                            \
        float s0v = fast_rcp(1.0f + exp2_fast(grz));  /* r (lo) / z (hi) */     \
        float zz  = __shfl_xor(s0v, 32, 64);          /* z on lo-lanes */       \
        float gn  = aN[0] + aN[1] + bias_nh2;                                   \
        float t0  = fast_rcp(1.0f + exp2_fast(fmaf(s0v, gn, (GXN))));           \
        float n0  = fmaf(-2.0f, t0, 1.0f);                                      \
        h0 = fmaf(zz, h0 - n0, n0);                   /* valid on lo-lanes */   \
        if (ln < 32) {                                                          \
            char* w_ = wbase + (1 - (RBUF)) * 1280;                             \
            unsigned short s0 = f2bf(h0);                                       \
            *(unsigned short*)(w_)       = s0;                                  \
            *(unsigned short*)(w_ + 320) = f2bf(h0 - bf2f(s0));                 \
        }                                                                       \
        __syncthreads();                                                        \
    }

    for (int it = 0; it < TT / 2; ++it) {
        // prefetch x(t+2), x(t+3) -- consumed by DOTS (2 per STEP, balanced)
        int t2 = 2 * it + 2; if (t2 > TT - 1) t2 = TT - 1;
        int t3 = t2 + 1;     if (t3 > TT - 1) t3 = TT - 1;
        float4 pa = *(const float4*)(xp + (size_t)t2 * II);
        float4 pb = *(const float4*)(xp + (size_t)t2 * II + 4);
        float4 pc = *(const float4*)(xp + (size_t)t3 * II);
        float4 pd = *(const float4*)(xp + (size_t)t3 * II + 4);

        STEP(0, grz0, gn0, {                    // even t: read buf0, write buf1
            grz0n = dot8(wrz, pa, pb, bias_rz2);
            gn0n  = dot8(wn,  pa, pb, bias_nx2);
        })
        STEP(1, grz1, gn1, {                    // odd  t: read buf1, write buf0
            grz1n = dot8(wrz, pc, pd, bias_rz2);
            gn1n  = dot8(wn,  pc, pd, bias_nx2);
        })
        grz0 = grz0n; gn0 = gn0n;
        grz1 = grz1n; gn1 = gn1n;
    }
#undef STEP
#undef MFMA_BF16

    // ---- epilogue FC on fp32 h ----
    if (ln < 32) hfin[b][j] = h0;
    __syncthreads();

    if (tid < 2 * OO) {
        const int bb2 = (tid >= OO) ? 1 : 0;
        const int o   = tid - OO * bb2;
        const float4* hf = (const float4*)(&hfin[bb2][0]);
        const float4* wp = (const float4*)(fc_w + o * HH);
        float acc = fc_b[o];
#pragma unroll 8
        for (int v = 0; v < HH / 4; ++v) {
            float4 w4 = wp[v];
            float4 h4 = hf[v];
            acc = fmaf(w4.x, h4.x, acc); acc = fmaf(w4.y, h4.y, acc);
            acc = fmaf(w4.z, h4.z, acc); acc = fmaf(w4.w, h4.w, acc);
        }
        out[(size_t)(b0 + bb2) * OO + o] = acc;
    }
}

extern "C" void kernel_launch(void* const* d_in, const int* in_sizes, int n_in,
                              void* d_out, int out_size, void* d_ws, size_t ws_size,
                              hipStream_t stream) {
    const float* x    = (const float*)d_in[0];
    const float* w_ih = (const float*)d_in[1];
    const float* w_hh = (const float*)d_in[2];
    const float* b_ih = (const float*)d_in[3];
    const float* b_hh = (const float*)d_in[4];
    const float* fc_w = (const float*)d_in[5];
    const float* fc_b = (const float*)d_in[6];
    float* out = (float*)d_out;

    gru_kernel<<<BB / 2, 512, 0, stream>>>(x, w_ih, w_hh, b_ih, b_hh, fc_w, fc_b, out);
}